// Round 1
// baseline (971.309 us; speedup 1.0000x reference)
//
#include <hip/hip_runtime.h>

#define B 4
#define L 2048
#define C 64
#define R 8
#define NCH (B * C)      // 256 chains
#define TQ 16            // timesteps per chunk (64->16: 4x waves, 16/CU occupancy)
#define S (L / TQ)       // 128 chunks per chain
#define GRP (NCH / 8)    // 32 chain-groups (8 chains per wave)

// Workspace (float2): sumP [S][NCH][8][8] (16 MB), sumQ [S][NCH][8] (2 MB),
// carry [S][NCH][8] (2 MB). Total ~21 MB.
//
// Lane mapping everywhere: lane = c*8 + r  (c = chain-in-group, r = row).
// LDS A-tile is XOR-row-swizzled: row p of chain c lives at slot (p^c), so
// the broadcast read of row k (address 256c + 32(k^c) bytes) spreads the 8
// chains over 4 bank-groups (2-way = free) instead of 8-way on one group.

// ---------------- Phase 1: chunk summaries ----------------
__global__ __launch_bounds__(64, 4) void k_summary(
    const float* __restrict__ Are, const float* __restrict__ Aim,
    const float* __restrict__ Xre, const float* __restrict__ Xim,
    float2* __restrict__ sumP, float2* __restrict__ sumQ)
{
    __shared__ __align__(16) float sm[1152]; // Are[512] Aim[512] Xre[64] Xim[64]
    const int lane = threadIdx.x;
    const int c = lane >> 3, r = lane & 7;
    const int s = blockIdx.x >> 5;       // chunk
    const int g = blockIdx.x & 31;       // chain-group
    const int n0 = g * 8;
    const int b = n0 >> 6;
    const int cc0 = n0 & (C - 1);
    const int n = n0 + c;
    const int tbase = s * TQ;
    const int sIdx = c * 16 + ((r ^ c) << 1);  // swizzled float4 slot for this lane's row

    float Pre[8], Pim[8];
#pragma unroll
    for (int k = 0; k < 8; ++k) { Pre[k] = (k == r) ? 1.f : 0.f; Pim[k] = 0.f; }
    float qre = 0.f, qim = 0.f;

    float4 sa0, sa1, si0, si1; float sxr, sxi;   // pipeline set 0
    float4 ta0, ta1, ti0, ti1; float txr, txi;   // pipeline set 1

#define LOADSET1(t, A0, A1, I0, I1, XR, XI)                                    \
    {                                                                          \
        const int fb = (b * L + (t)) * C + cc0;                                \
        const float4* pA = (const float4*)(Are + (long)fb * 64) + lane * 2;    \
        const float4* pI = (const float4*)(Aim + (long)fb * 64) + lane * 2;    \
        A0 = pA[0]; A1 = pA[1]; I0 = pI[0]; I1 = pI[1];                        \
        XR = Xre[(long)fb * 8 + lane]; XI = Xim[(long)fb * 8 + lane];          \
    }

#define STAGESET1(A0, A1, I0, I1, XR, XI)                                      \
    {                                                                          \
        float4* s4 = (float4*)sm;                                              \
        s4[sIdx] = A0; s4[sIdx + 1] = A1;                                      \
        s4[128 + sIdx] = I0; s4[128 + sIdx + 1] = I1;                          \
        sm[1024 + lane] = XR; sm[1088 + lane] = XI;                            \
    }

#define COMPUTE_STEP1()                                                        \
    {                                                                          \
        float xr[8], xi[8];                                                    \
        *(float4*)&xr[0] = *(const float4*)(sm + 1024 + c * 8);                \
        *(float4*)&xr[4] = *(const float4*)(sm + 1024 + c * 8 + 4);            \
        *(float4*)&xi[0] = *(const float4*)(sm + 1088 + c * 8);                \
        *(float4*)&xi[4] = *(const float4*)(sm + 1088 + c * 8 + 4);            \
        _Pragma("unroll")                                                      \
        for (int k = 0; k < 8; ++k) {                                          \
            qre += Pre[k] * xr[k] - Pim[k] * xi[k];                            \
            qim += Pre[k] * xi[k] + Pim[k] * xr[k];                            \
        }                                                                      \
        float Nre[8], Nim[8];                                                  \
        _Pragma("unroll")                                                      \
        for (int j = 0; j < 8; ++j) { Nre[j] = 0.f; Nim[j] = 0.f; }            \
        _Pragma("unroll")                                                      \
        for (int k = 0; k < 8; ++k) {                                          \
            const int ko = ((k ^ c) << 3);  /* slot of row k under swizzle */  \
            float er[8], ei[8];                                                \
            *(float4*)&er[0] = *(const float4*)(sm + c * 64 + ko);             \
            *(float4*)&er[4] = *(const float4*)(sm + c * 64 + ko + 4);         \
            *(float4*)&ei[0] = *(const float4*)(sm + 512 + c * 64 + ko);       \
            *(float4*)&ei[4] = *(const float4*)(sm + 512 + c * 64 + ko + 4);   \
            const float pr = Pre[k], pi = Pim[k];                              \
            _Pragma("unroll")                                                  \
            for (int j = 0; j < 8; ++j) {                                      \
                Nre[j] += pr * er[j] - pi * ei[j];                             \
                Nim[j] += pr * ei[j] + pi * er[j];                             \
            }                                                                  \
        }                                                                      \
        _Pragma("unroll")                                                      \
        for (int k = 0; k < 8; ++k) { Pre[k] = Nre[k]; Pim[k] = Nim[k]; }      \
    }

    LOADSET1(tbase + TQ - 1, sa0, sa1, si0, si1, sxr, sxi);
    LOADSET1(tbase + TQ - 2, ta0, ta1, ti0, ti1, txr, txi);

#pragma unroll 1
    for (int tt = TQ - 1; tt >= 1; tt -= 2) {
        STAGESET1(sa0, sa1, si0, si1, sxr, sxi);
        if (tt >= 3) LOADSET1(tbase + tt - 2, sa0, sa1, si0, si1, sxr, sxi);
        COMPUTE_STEP1();
        STAGESET1(ta0, ta1, ti0, ti1, txr, txi);
        if (tt >= 3) LOADSET1(tbase + tt - 3, ta0, ta1, ti0, ti1, txr, txi);
        COMPUTE_STEP1();
    }

    // store P row r (8 complex) and q
    float4* gp = (float4*)(sumP + ((long)(s * 256 + n) * 8 + r) * 8);
    gp[0] = make_float4(Pre[0], Pim[0], Pre[1], Pim[1]);
    gp[1] = make_float4(Pre[2], Pim[2], Pre[3], Pim[3]);
    gp[2] = make_float4(Pre[4], Pim[4], Pre[5], Pim[5]);
    gp[3] = make_float4(Pre[6], Pim[6], Pre[7], Pim[7]);
    sumQ[(long)(s * 256 + n) * 8 + r] = make_float2(qre, qim);
}

// ---------------- Phase 2: carry scan over chunks ----------------
__global__ __launch_bounds__(64) void k_carry(
    const float2* __restrict__ sumP, const float2* __restrict__ sumQ,
    float2* __restrict__ carry)
{
    __shared__ __align__(16) float cb[160];  // stride-20 per chain: conflict-free bcast
    const int lane = threadIdx.x;
    const int c = lane >> 3, r = lane & 7;
    const int n = blockIdx.x * 8 + c;

    float yr = 0.f, yi = 0.f;    // carry into chunk 0 is zero
    long base = (long)n * 8;
    // prefetch chunk 0's summary
    const float4* prow0 = (const float4*)(sumP + (base + r) * 8);
    float4 p0 = prow0[0], p1 = prow0[1], p2 = prow0[2], p3 = prow0[3];
    float2 qv = sumQ[base + r];

#pragma unroll 1
    for (int s = 0; s < S; ++s) {
        carry[base + r] = make_float2(yr, yi);
        *(float2*)(cb + c * 20 + 2 * r) = make_float2(yr, yi);
        float4 w0 = p0, w1 = p1, w2 = p2, w3 = p3;
        float2 q = qv;
        if (s + 1 < S) {  // prefetch next chunk while broadcast settles
            const long nb = base + 2048;
            const float4* np = (const float4*)(sumP + (nb + r) * 8);
            p0 = np[0]; p1 = np[1]; p2 = np[2]; p3 = np[3];
            qv = sumQ[nb + r];
        }
        float yvr[8], yvi[8];
        {
            float4 u0 = *(const float4*)(cb + c * 20);
            float4 u1 = *(const float4*)(cb + c * 20 + 4);
            float4 u2 = *(const float4*)(cb + c * 20 + 8);
            float4 u3 = *(const float4*)(cb + c * 20 + 12);
            yvr[0]=u0.x; yvi[0]=u0.y; yvr[1]=u0.z; yvi[1]=u0.w;
            yvr[2]=u1.x; yvi[2]=u1.y; yvr[3]=u1.z; yvi[3]=u1.w;
            yvr[4]=u2.x; yvi[4]=u2.y; yvr[5]=u2.z; yvi[5]=u2.w;
            yvr[6]=u3.x; yvi[6]=u3.y; yvr[7]=u3.z; yvi[7]=u3.w;
        }
        float prr[8], pri[8];
        prr[0]=w0.x; pri[0]=w0.y; prr[1]=w0.z; pri[1]=w0.w;
        prr[2]=w1.x; pri[2]=w1.y; prr[3]=w1.z; pri[3]=w1.w;
        prr[4]=w2.x; pri[4]=w2.y; prr[5]=w2.z; pri[5]=w2.w;
        prr[6]=w3.x; pri[6]=w3.y; prr[7]=w3.z; pri[7]=w3.w;
        float nr0 = q.x, ni0 = q.y, nr1 = 0.f, ni1 = 0.f;  // dual accum: halve dep chain
#pragma unroll
        for (int k = 0; k < 8; k += 2) {
            nr0 += prr[k] * yvr[k] - pri[k] * yvi[k];
            ni0 += prr[k] * yvi[k] + pri[k] * yvr[k];
            nr1 += prr[k+1] * yvr[k+1] - pri[k+1] * yvi[k+1];
            ni1 += prr[k+1] * yvi[k+1] + pri[k+1] * yvr[k+1];
        }
        yr = nr0 + nr1; yi = ni0 + ni1;
        base += 2048;
    }
}

// ---------------- Phase 3: fixup + output ----------------
// A never goes through LDS here: lane (c,r) only needs its OWN row r of A_t
// (the old LDS staging was an identity round trip). Only the carry vector is
// broadcast, via a stride-20-padded LDS buffer.
__global__ __launch_bounds__(64, 4) void k_fixup(
    const float* __restrict__ Are, const float* __restrict__ Aim,
    const float* __restrict__ Xre, const float* __restrict__ Xim,
    const float2* __restrict__ carry, float2* __restrict__ out)
{
    __shared__ __align__(16) float cb[160];
    const int lane = threadIdx.x;
    const int c = lane >> 3, r = lane & 7;
    const int blk = (int)gridDim.x - 1 - (int)blockIdx.x;  // reversed for L3 reuse
    const int s = blk >> 5;
    const int g = blk & 31;
    const int n0 = g * 8;
    const int b = n0 >> 6;
    const int cc0 = n0 & (C - 1);
    const int n = n0 + c;
    const int tbase = s * TQ;

    float yvr[8], yvi[8];
    {
        const float4* cv = (const float4*)(carry + (long)(s * 256 + n) * 8);
        float4 w0 = cv[0], w1 = cv[1], w2 = cv[2], w3 = cv[3];
        yvr[0]=w0.x; yvi[0]=w0.y; yvr[1]=w0.z; yvi[1]=w0.w;
        yvr[2]=w1.x; yvi[2]=w1.y; yvr[3]=w1.z; yvi[3]=w1.w;
        yvr[4]=w2.x; yvi[4]=w2.y; yvr[5]=w2.z; yvi[5]=w2.w;
        yvr[6]=w3.x; yvi[6]=w3.y; yvr[7]=w3.z; yvi[7]=w3.w;
    }

    float4 sa0, sa1, si0, si1; float sxr, sxi;
    float4 ta0, ta1, ti0, ti1; float txr, txi;

#define LOADSET3(t, A0, A1, I0, I1, XR, XI)                                    \
    {                                                                          \
        const int fb = (b * L + (t)) * C + cc0;                                \
        const float4* pA = (const float4*)(Are + (long)fb * 64) + lane * 2;    \
        const float4* pI = (const float4*)(Aim + (long)fb * 64) + lane * 2;    \
        A0 = pA[0]; A1 = pA[1]; I0 = pI[0]; I1 = pI[1];                        \
        XR = Xre[(long)fb * 8 + lane]; XI = Xim[(long)fb * 8 + lane];          \
    }

#define FIX_STEP(A0, A1, I0, I1, XR_, XI_, t)                                  \
    {                                                                          \
        float nr0 = (XR_), ni0 = (XI_), nr1 = 0.f, ni1 = 0.f;                  \
        nr0 += A0.x * yvr[0] - I0.x * yvi[0];                                  \
        ni0 += A0.x * yvi[0] + I0.x * yvr[0];                                  \
        nr1 += A0.y * yvr[1] - I0.y * yvi[1];                                  \
        ni1 += A0.y * yvi[1] + I0.y * yvr[1];                                  \
        nr0 += A0.z * yvr[2] - I0.z * yvi[2];                                  \
        ni0 += A0.z * yvi[2] + I0.z * yvr[2];                                  \
        nr1 += A0.w * yvr[3] - I0.w * yvi[3];                                  \
        ni1 += A0.w * yvi[3] + I0.w * yvr[3];                                  \
        nr0 += A1.x * yvr[4] - I1.x * yvi[4];                                  \
        ni0 += A1.x * yvi[4] + I1.x * yvr[4];                                  \
        nr1 += A1.y * yvr[5] - I1.y * yvi[5];                                  \
        ni1 += A1.y * yvi[5] + I1.y * yvr[5];                                  \
        nr0 += A1.z * yvr[6] - I1.z * yvi[6];                                  \
        ni0 += A1.z * yvi[6] + I1.z * yvr[6];                                  \
        nr1 += A1.w * yvr[7] - I1.w * yvi[7];                                  \
        ni1 += A1.w * yvi[7] + I1.w * yvr[7];                                  \
        const float nr = nr0 + nr1, ni = ni0 + ni1;                            \
        const int fb = (b * L + (t)) * C + cc0;                                \
        out[(long)fb * 8 + lane] = make_float2(nr, ni);                        \
        *(float2*)(cb + c * 20 + 2 * r) = make_float2(nr, ni);                 \
        float4 u0 = *(const float4*)(cb + c * 20);                             \
        float4 u1 = *(const float4*)(cb + c * 20 + 4);                         \
        float4 u2 = *(const float4*)(cb + c * 20 + 8);                         \
        float4 u3 = *(const float4*)(cb + c * 20 + 12);                        \
        yvr[0]=u0.x; yvi[0]=u0.y; yvr[1]=u0.z; yvi[1]=u0.w;                    \
        yvr[2]=u1.x; yvi[2]=u1.y; yvr[3]=u1.z; yvi[3]=u1.w;                    \
        yvr[4]=u2.x; yvi[4]=u2.y; yvr[5]=u2.z; yvi[5]=u2.w;                    \
        yvr[6]=u3.x; yvi[6]=u3.y; yvr[7]=u3.z; yvi[7]=u3.w;                    \
    }

    LOADSET3(tbase + 0, sa0, sa1, si0, si1, sxr, sxi);
    LOADSET3(tbase + 1, ta0, ta1, ti0, ti1, txr, txi);

#pragma unroll 1
    for (int tt = 0; tt < TQ; tt += 2) {
        float4 A0 = sa0, A1 = sa1, I0 = si0, I1 = si1;
        float XR = sxr, XI = sxi;
        if (tt + 2 < TQ) LOADSET3(tbase + tt + 2, sa0, sa1, si0, si1, sxr, sxi);
        FIX_STEP(A0, A1, I0, I1, XR, XI, tbase + tt);
        float4 B0 = ta0, B1 = ta1, J0 = ti0, J1 = ti1;
        float YR = txr, YI = txi;
        if (tt + 3 < TQ) LOADSET3(tbase + tt + 3, ta0, ta1, ti0, ti1, txr, txi);
        FIX_STEP(B0, B1, J0, J1, YR, YI, tbase + tt + 1);
    }
}

extern "C" void kernel_launch(void* const* d_in, const int* in_sizes, int n_in,
                              void* d_out, int out_size, void* d_ws, size_t ws_size,
                              hipStream_t stream)
{
    const float* Are = (const float*)d_in[0];
    const float* Aim = (const float*)d_in[1];
    const float* Xre = (const float*)d_in[2];
    const float* Xim = (const float*)d_in[3];
    float2* out = (float2*)d_out;

    float2* sumP  = (float2*)d_ws;                    // S*NCH*64 float2 (16 MB)
    float2* sumQ  = sumP + (long)S * NCH * 64;        // S*NCH*8  float2 (2 MB)
    float2* carry = sumQ + (long)S * NCH * 8;         // S*NCH*8  float2 (2 MB)

    k_summary<<<S * GRP, 64, 0, stream>>>(Are, Aim, Xre, Xim, sumP, sumQ);
    k_carry<<<NCH / 8, 64, 0, stream>>>(sumP, sumQ, carry);
    k_fixup<<<S * GRP, 64, 0, stream>>>(Are, Aim, Xre, Xim, carry, out);
}

// Round 2
// 432.528 us; speedup vs baseline: 2.2457x; 2.2457x over previous
//
#include <hip/hip_runtime.h>

#define B 4
#define L 2048
#define C 64
#define R 8
#define NCH (B * C)      // 256 chains
#define TQ 16            // timesteps per chunk: S*GRP=4096 waves -> 16 waves/CU
#define S (L / TQ)       // 128 chunks per chain
#define GRP (NCH / 8)    // 32 chain-groups (8 chains per wave)

// Workspace (float2): sumP [S][NCH][8][8] (16 MB), sumQ [S][NCH][8] (2 MB),
// carry [S][NCH][8] (2 MB). Total ~21 MB.
//
// Lane mapping everywhere: lane = c*8 + r  (c = chain-in-group, r = row).
// LDS A-tile is XOR-row-swizzled: row p of chain c lives at slot (p^c), so
// the broadcast read of row k spreads the 8 chains over 4 bank-groups
// (2-way = free) instead of 8-way on one group.
// NOTE: no min-waves arg on __launch_bounds__ — forcing 4 waves/EU made the
// compiler cap VGPR at 64 and spill (FETCH 147MB->999MB, WRITE->1.5GB).
// Plain (64) gives ~120 VGPR = 16 waves/CU tier with zero scratch.

// ---------------- Phase 1: chunk summaries ----------------
__global__ __launch_bounds__(64) void k_summary(
    const float* __restrict__ Are, const float* __restrict__ Aim,
    const float* __restrict__ Xre, const float* __restrict__ Xim,
    float2* __restrict__ sumP, float2* __restrict__ sumQ)
{
    __shared__ __align__(16) float sm[1152]; // Are[512] Aim[512] Xre[64] Xim[64]
    const int lane = threadIdx.x;
    const int c = lane >> 3, r = lane & 7;
    const int s = blockIdx.x >> 5;       // chunk
    const int g = blockIdx.x & 31;       // chain-group
    const int n0 = g * 8;
    const int b = n0 >> 6;
    const int cc0 = n0 & (C - 1);
    const int n = n0 + c;
    const int tbase = s * TQ;
    const int sIdx = c * 16 + ((r ^ c) << 1);  // swizzled float4 slot for this lane's row

    float Pre[8], Pim[8];
#pragma unroll
    for (int k = 0; k < 8; ++k) { Pre[k] = (k == r) ? 1.f : 0.f; Pim[k] = 0.f; }
    float qre = 0.f, qim = 0.f;

    float4 sa0, sa1, si0, si1; float sxr, sxi;   // pipeline set 0
    float4 ta0, ta1, ti0, ti1; float txr, txi;   // pipeline set 1

#define LOADSET1(t, A0, A1, I0, I1, XR, XI)                                    \
    {                                                                          \
        const int fb = (b * L + (t)) * C + cc0;                                \
        const float4* pA = (const float4*)(Are + (long)fb * 64) + lane * 2;    \
        const float4* pI = (const float4*)(Aim + (long)fb * 64) + lane * 2;    \
        A0 = pA[0]; A1 = pA[1]; I0 = pI[0]; I1 = pI[1];                        \
        XR = Xre[(long)fb * 8 + lane]; XI = Xim[(long)fb * 8 + lane];          \
    }

#define STAGESET1(A0, A1, I0, I1, XR, XI)                                      \
    {                                                                          \
        float4* s4 = (float4*)sm;                                              \
        s4[sIdx] = A0; s4[sIdx + 1] = A1;                                      \
        s4[128 + sIdx] = I0; s4[128 + sIdx + 1] = I1;                          \
        sm[1024 + lane] = XR; sm[1088 + lane] = XI;                            \
    }

#define COMPUTE_STEP1()                                                        \
    {                                                                          \
        float xr[8], xi[8];                                                    \
        *(float4*)&xr[0] = *(const float4*)(sm + 1024 + c * 8);                \
        *(float4*)&xr[4] = *(const float4*)(sm + 1024 + c * 8 + 4);            \
        *(float4*)&xi[0] = *(const float4*)(sm + 1088 + c * 8);                \
        *(float4*)&xi[4] = *(const float4*)(sm + 1088 + c * 8 + 4);            \
        _Pragma("unroll")                                                      \
        for (int k = 0; k < 8; ++k) {                                          \
            qre += Pre[k] * xr[k] - Pim[k] * xi[k];                            \
            qim += Pre[k] * xi[k] + Pim[k] * xr[k];                            \
        }                                                                      \
        float Nre[8], Nim[8];                                                  \
        _Pragma("unroll")                                                      \
        for (int j = 0; j < 8; ++j) { Nre[j] = 0.f; Nim[j] = 0.f; }            \
        _Pragma("unroll")                                                      \
        for (int k = 0; k < 8; ++k) {                                          \
            const int ko = ((k ^ c) << 3);  /* slot of row k under swizzle */  \
            float er[8], ei[8];                                                \
            *(float4*)&er[0] = *(const float4*)(sm + c * 64 + ko);             \
            *(float4*)&er[4] = *(const float4*)(sm + c * 64 + ko + 4);         \
            *(float4*)&ei[0] = *(const float4*)(sm + 512 + c * 64 + ko);       \
            *(float4*)&ei[4] = *(const float4*)(sm + 512 + c * 64 + ko + 4);   \
            const float pr = Pre[k], pi = Pim[k];                              \
            _Pragma("unroll")                                                  \
            for (int j = 0; j < 8; ++j) {                                      \
                Nre[j] += pr * er[j] - pi * ei[j];                             \
                Nim[j] += pr * ei[j] + pi * er[j];                             \
            }                                                                  \
        }                                                                      \
        _Pragma("unroll")                                                      \
        for (int k = 0; k < 8; ++k) { Pre[k] = Nre[k]; Pim[k] = Nim[k]; }      \
    }

    LOADSET1(tbase + TQ - 1, sa0, sa1, si0, si1, sxr, sxi);
    LOADSET1(tbase + TQ - 2, ta0, ta1, ti0, ti1, txr, txi);

#pragma unroll 1
    for (int tt = TQ - 1; tt >= 1; tt -= 2) {
        STAGESET1(sa0, sa1, si0, si1, sxr, sxi);
        if (tt >= 3) LOADSET1(tbase + tt - 2, sa0, sa1, si0, si1, sxr, sxi);
        COMPUTE_STEP1();
        STAGESET1(ta0, ta1, ti0, ti1, txr, txi);
        if (tt >= 3) LOADSET1(tbase + tt - 3, ta0, ta1, ti0, ti1, txr, txi);
        COMPUTE_STEP1();
    }

    // store P row r (8 complex) and q
    float4* gp = (float4*)(sumP + ((long)(s * 256 + n) * 8 + r) * 8);
    gp[0] = make_float4(Pre[0], Pim[0], Pre[1], Pim[1]);
    gp[1] = make_float4(Pre[2], Pim[2], Pre[3], Pim[3]);
    gp[2] = make_float4(Pre[4], Pim[4], Pre[5], Pim[5]);
    gp[3] = make_float4(Pre[6], Pim[6], Pre[7], Pim[7]);
    sumQ[(long)(s * 256 + n) * 8 + r] = make_float2(qre, qim);
}

// ---------------- Phase 2: carry scan over chunks ----------------
__global__ __launch_bounds__(64) void k_carry(
    const float2* __restrict__ sumP, const float2* __restrict__ sumQ,
    float2* __restrict__ carry)
{
    __shared__ __align__(16) float cb[160];  // stride-20 per chain: conflict-free bcast
    const int lane = threadIdx.x;
    const int c = lane >> 3, r = lane & 7;
    const int n = blockIdx.x * 8 + c;

    float yr = 0.f, yi = 0.f;    // carry into chunk 0 is zero
    long base = (long)n * 8;
    // prefetch chunk 0's summary
    const float4* prow0 = (const float4*)(sumP + (base + r) * 8);
    float4 p0 = prow0[0], p1 = prow0[1], p2 = prow0[2], p3 = prow0[3];
    float2 qv = sumQ[base + r];

#pragma unroll 1
    for (int s = 0; s < S; ++s) {
        carry[base + r] = make_float2(yr, yi);
        *(float2*)(cb + c * 20 + 2 * r) = make_float2(yr, yi);
        float4 w0 = p0, w1 = p1, w2 = p2, w3 = p3;
        float2 q = qv;
        if (s + 1 < S) {  // prefetch next chunk while broadcast settles
            const long nb = base + 2048;
            const float4* np = (const float4*)(sumP + (nb + r) * 8);
            p0 = np[0]; p1 = np[1]; p2 = np[2]; p3 = np[3];
            qv = sumQ[nb + r];
        }
        float yvr[8], yvi[8];
        {
            float4 u0 = *(const float4*)(cb + c * 20);
            float4 u1 = *(const float4*)(cb + c * 20 + 4);
            float4 u2 = *(const float4*)(cb + c * 20 + 8);
            float4 u3 = *(const float4*)(cb + c * 20 + 12);
            yvr[0]=u0.x; yvi[0]=u0.y; yvr[1]=u0.z; yvi[1]=u0.w;
            yvr[2]=u1.x; yvi[2]=u1.y; yvr[3]=u1.z; yvi[3]=u1.w;
            yvr[4]=u2.x; yvi[4]=u2.y; yvr[5]=u2.z; yvi[5]=u2.w;
            yvr[6]=u3.x; yvi[6]=u3.y; yvr[7]=u3.z; yvi[7]=u3.w;
        }
        float prr[8], pri[8];
        prr[0]=w0.x; pri[0]=w0.y; prr[1]=w0.z; pri[1]=w0.w;
        prr[2]=w1.x; pri[2]=w1.y; prr[3]=w1.z; pri[3]=w1.w;
        prr[4]=w2.x; pri[4]=w2.y; prr[5]=w2.z; pri[5]=w2.w;
        prr[6]=w3.x; pri[6]=w3.y; prr[7]=w3.z; pri[7]=w3.w;
        float nr0 = q.x, ni0 = q.y, nr1 = 0.f, ni1 = 0.f;  // dual accum: halve dep chain
#pragma unroll
        for (int k = 0; k < 8; k += 2) {
            nr0 += prr[k] * yvr[k] - pri[k] * yvi[k];
            ni0 += prr[k] * yvi[k] + pri[k] * yvr[k];
            nr1 += prr[k+1] * yvr[k+1] - pri[k+1] * yvi[k+1];
            ni1 += prr[k+1] * yvi[k+1] + pri[k+1] * yvr[k+1];
        }
        yr = nr0 + nr1; yi = ni0 + ni1;
        base += 2048;
    }
}

// ---------------- Phase 3: fixup + output ----------------
// A never goes through LDS here: lane (c,r) only needs its OWN row r of A_t
// (the old LDS staging was an identity round trip). Only the carry vector is
// broadcast, via a stride-20-padded LDS buffer.
__global__ __launch_bounds__(64) void k_fixup(
    const float* __restrict__ Are, const float* __restrict__ Aim,
    const float* __restrict__ Xre, const float* __restrict__ Xim,
    const float2* __restrict__ carry, float2* __restrict__ out)
{
    __shared__ __align__(16) float cb[160];
    const int lane = threadIdx.x;
    const int c = lane >> 3, r = lane & 7;
    const int blk = (int)gridDim.x - 1 - (int)blockIdx.x;  // reversed for L3 reuse
    const int s = blk >> 5;
    const int g = blk & 31;
    const int n0 = g * 8;
    const int b = n0 >> 6;
    const int cc0 = n0 & (C - 1);
    const int n = n0 + c;
    const int tbase = s * TQ;

    float yvr[8], yvi[8];
    {
        const float4* cv = (const float4*)(carry + (long)(s * 256 + n) * 8);
        float4 w0 = cv[0], w1 = cv[1], w2 = cv[2], w3 = cv[3];
        yvr[0]=w0.x; yvi[0]=w0.y; yvr[1]=w0.z; yvi[1]=w0.w;
        yvr[2]=w1.x; yvi[2]=w1.y; yvr[3]=w1.z; yvi[3]=w1.w;
        yvr[4]=w2.x; yvi[4]=w2.y; yvr[5]=w2.z; yvi[5]=w2.w;
        yvr[6]=w3.x; yvi[6]=w3.y; yvr[7]=w3.z; yvi[7]=w3.w;
    }

    float4 sa0, sa1, si0, si1; float sxr, sxi;
    float4 ta0, ta1, ti0, ti1; float txr, txi;

#define LOADSET3(t, A0, A1, I0, I1, XR, XI)                                    \
    {                                                                          \
        const int fb = (b * L + (t)) * C + cc0;                                \
        const float4* pA = (const float4*)(Are + (long)fb * 64) + lane * 2;    \
        const float4* pI = (const float4*)(Aim + (long)fb * 64) + lane * 2;    \
        A0 = pA[0]; A1 = pA[1]; I0 = pI[0]; I1 = pI[1];                        \
        XR = Xre[(long)fb * 8 + lane]; XI = Xim[(long)fb * 8 + lane];          \
    }

#define FIX_STEP(A0, A1, I0, I1, XR_, XI_, t)                                  \
    {                                                                          \
        float nr0 = (XR_), ni0 = (XI_), nr1 = 0.f, ni1 = 0.f;                  \
        nr0 += A0.x * yvr[0] - I0.x * yvi[0];                                  \
        ni0 += A0.x * yvi[0] + I0.x * yvr[0];                                  \
        nr1 += A0.y * yvr[1] - I0.y * yvi[1];                                  \
        ni1 += A0.y * yvi[1] + I0.y * yvr[1];                                  \
        nr0 += A0.z * yvr[2] - I0.z * yvi[2];                                  \
        ni0 += A0.z * yvi[2] + I0.z * yvr[2];                                  \
        nr1 += A0.w * yvr[3] - I0.w * yvi[3];                                  \
        ni1 += A0.w * yvi[3] + I0.w * yvr[3];                                  \
        nr0 += A1.x * yvr[4] - I1.x * yvi[4];                                  \
        ni0 += A1.x * yvi[4] + I1.x * yvr[4];                                  \
        nr1 += A1.y * yvr[5] - I1.y * yvi[5];                                  \
        ni1 += A1.y * yvi[5] + I1.y * yvr[5];                                  \
        nr0 += A1.z * yvr[6] - I1.z * yvi[6];                                  \
        ni0 += A1.z * yvi[6] + I1.z * yvr[6];                                  \
        nr1 += A1.w * yvr[7] - I1.w * yvi[7];                                  \
        ni1 += A1.w * yvi[7] + I1.w * yvr[7];                                  \
        const float nr = nr0 + nr1, ni = ni0 + ni1;                            \
        const int fb = (b * L + (t)) * C + cc0;                                \
        out[(long)fb * 8 + lane] = make_float2(nr, ni);                        \
        *(float2*)(cb + c * 20 + 2 * r) = make_float2(nr, ni);                 \
        float4 u0 = *(const float4*)(cb + c * 20);                             \
        float4 u1 = *(const float4*)(cb + c * 20 + 4);                         \
        float4 u2 = *(const float4*)(cb + c * 20 + 8);                         \
        float4 u3 = *(const float4*)(cb + c * 20 + 12);                        \
        yvr[0]=u0.x; yvi[0]=u0.y; yvr[1]=u0.z; yvi[1]=u0.w;                    \
        yvr[2]=u1.x; yvi[2]=u1.y; yvr[3]=u1.z; yvi[3]=u1.w;                    \
        yvr[4]=u2.x; yvi[4]=u2.y; yvr[5]=u2.z; yvi[5]=u2.w;                    \
        yvr[6]=u3.x; yvi[6]=u3.y; yvr[7]=u3.z; yvi[7]=u3.w;                    \
    }

    LOADSET3(tbase + 0, sa0, sa1, si0, si1, sxr, sxi);
    LOADSET3(tbase + 1, ta0, ta1, ti0, ti1, txr, txi);

#pragma unroll 1
    for (int tt = 0; tt < TQ; tt += 2) {
        float4 A0 = sa0, A1 = sa1, I0 = si0, I1 = si1;
        float XR = sxr, XI = sxi;
        if (tt + 2 < TQ) LOADSET3(tbase + tt + 2, sa0, sa1, si0, si1, sxr, sxi);
        FIX_STEP(A0, A1, I0, I1, XR, XI, tbase + tt);
        float4 B0 = ta0, B1 = ta1, J0 = ti0, J1 = ti1;
        float YR = txr, YI = txi;
        if (tt + 3 < TQ) LOADSET3(tbase + tt + 3, ta0, ta1, ti0, ti1, txr, txi);
        FIX_STEP(B0, B1, J0, J1, YR, YI, tbase + tt + 1);
    }
}

extern "C" void kernel_launch(void* const* d_in, const int* in_sizes, int n_in,
                              void* d_out, int out_size, void* d_ws, size_t ws_size,
                              hipStream_t stream)
{
    const float* Are = (const float*)d_in[0];
    const float* Aim = (const float*)d_in[1];
    const float* Xre = (const float*)d_in[2];
    const float* Xim = (const float*)d_in[3];
    float2* out = (float2*)d_out;

    float2* sumP  = (float2*)d_ws;                    // S*NCH*64 float2 (16 MB)
    float2* sumQ  = sumP + (long)S * NCH * 64;        // S*NCH*8  float2 (2 MB)
    float2* carry = sumQ + (long)S * NCH * 8;         // S*NCH*8  float2 (2 MB)

    k_summary<<<S * GRP, 64, 0, stream>>>(Are, Aim, Xre, Xim, sumP, sumQ);
    k_carry<<<NCH / 8, 64, 0, stream>>>(sumP, sumQ, carry);
    k_fixup<<<S * GRP, 64, 0, stream>>>(Are, Aim, Xre, Xim, carry, out);
}